// Round 11
// baseline (428.775 us; speedup 1.0000x reference)
//
#include <hip/hip_runtime.h>
#include <hip/hip_bf16.h>

typedef __attribute__((ext_vector_type(8))) short bf16x8;
typedef __attribute__((ext_vector_type(4))) float f32x4;

__device__ __forceinline__ ushort bf16rne(float f) {
    uint u = __float_as_uint(f);
    return (ushort)((u + 0x7fffu + ((u >> 16) & 1u)) >> 16);
}
__device__ __forceinline__ void unpack2(uint p, float& a, float& b) {
    a = __uint_as_float(p << 16);
    b = __uint_as_float(p & 0xffff0000u);
}

// ---------------- bucketed graph preprocessing ----------------
// bucket = dst >> 8 (256 nodes per bucket), nbuck <= 512. Packed pair:
// (dst&255)<<24 | src  (src < 2^24).

__global__ __launch_bounds__(256) void k_bhist(const int* __restrict__ dst,
                                               int* __restrict__ bcnt, int E) {
    __shared__ int hist[512];
    int t = threadIdx.x;
    hist[t] = 0; hist[t + 256] = 0;
    __syncthreads();
    int off = blockIdx.x * 4096;
    int cnt = min(4096, E - off);
    for (int i = t; i < cnt; i += 256) atomicAdd(&hist[dst[off + i] >> 8], 1);
    __syncthreads();
    if (hist[t]) atomicAdd(&bcnt[t], hist[t]);
    if (hist[t + 256]) atomicAdd(&bcnt[t + 256], hist[t + 256]);
}

__global__ void k_bscan(const int* __restrict__ bcnt, int* __restrict__ bbase,
                        int* __restrict__ bcur, int nbuck) {
    __shared__ int s[512];
    int t = threadIdx.x;  // 512
    s[t] = (t < nbuck) ? bcnt[t] : 0;
    __syncthreads();
    for (int d = 1; d < 512; d <<= 1) {
        int u = (t >= d) ? s[t - d] : 0;
        __syncthreads();
        if (t >= d) s[t] += u;
        __syncthreads();
    }
    int excl = (t == 0) ? 0 : s[t - 1];
    bbase[t] = excl;
    if (t < nbuck) bcur[t] = excl;
    if (t == 511) bbase[512] = s[511];
}

__global__ __launch_bounds__(256) void k_binpack(const int* __restrict__ src,
                                                 const int* __restrict__ dst,
                                                 int* __restrict__ bcur,
                                                 uint* __restrict__ pairbuf,
                                                 int E, int nbuck) {
    __shared__ int hist[512];
    __shared__ int scn[512];
    __shared__ int cur[512];
    __shared__ int gbase[512];
    __shared__ uint sorted[4096];
    int t = threadIdx.x;
    int off = blockIdx.x * 4096;
    int cnt = min(4096, E - off);

    hist[t] = 0; hist[t + 256] = 0;
    __syncthreads();
    for (int i = t; i < cnt; i += 256) {
        int b = dst[off + i] >> 8;
        atomicAdd(&hist[b], 1);
    }
    __syncthreads();
    scn[t] = hist[t]; scn[t + 256] = hist[t + 256];
    __syncthreads();
    for (int d = 1; d < 256; d <<= 1) {
        int u0 = (t >= d) ? scn[t - d] : 0;
        int u1 = (t >= d) ? scn[256 + t - d] : 0;
        __syncthreads();
        if (t >= d) { scn[t] += u0; scn[256 + t] += u1; }
        __syncthreads();
    }
    int tot0 = scn[255];
    scn[256 + t] += tot0;
    __syncthreads();
    cur[t] = (t == 0) ? 0 : scn[t - 1];
    cur[t + 256] = scn[t + 255];
    if (t < nbuck && hist[t] > 0) gbase[t] = atomicAdd(&bcur[t], hist[t]);
    int t2 = t + 256;
    if (t2 < nbuck && hist[t2] > 0) gbase[t2] = atomicAdd(&bcur[t2], hist[t2]);
    __syncthreads();
    for (int i = t; i < cnt; i += 256) {
        int d = dst[off + i];
        int s = src[off + i];
        int b = d >> 8;
        int pos = atomicAdd(&cur[b], 1);
        sorted[pos] = ((uint)(d & 255) << 24) | (uint)s;
    }
    __syncthreads();
    int wid = t >> 6, lane = t & 63;
    for (int b = wid; b < nbuck; b += 4) {
        int n = hist[b];
        if (n == 0) continue;
        int ls = (b == 0) ? 0 : scn[b - 1];
        int gb = gbase[b];
        for (int j = lane; j < n; j += 64)
            pairbuf[gb + j] = sorted[ls + j];
    }
}

#define CSR_CAP 5632
__global__ __launch_bounds__(256) void k_csrbuild(const uint* __restrict__ pairbuf,
                                                  const int* __restrict__ bbase,
                                                  int* __restrict__ rowptr,
                                                  float* __restrict__ dinv,
                                                  int* __restrict__ csr,
                                                  int N, int nbuck) {
    __shared__ int lhist[256];
    __shared__ int scn[256];
    __shared__ int lcur[256];
    __shared__ int lcsr[CSR_CAP];
    int b = blockIdx.x;
    int base = b << 8;
    int nn = min(256, N - base);
    int lo = bbase[b], hi = bbase[b + 1];
    int cnt = hi - lo;
    int t = threadIdx.x;
    lhist[t] = 0;
    __syncthreads();
    for (int i = t; i < cnt; i += 256) atomicAdd(&lhist[pairbuf[lo + i] >> 24], 1);
    __syncthreads();
    int mydeg = lhist[t];
    scn[t] = mydeg;
    __syncthreads();
    for (int d = 1; d < 256; d <<= 1) {
        int u = (t >= d) ? scn[t - d] : 0;
        __syncthreads();
        if (t >= d) scn[t] += u;
        __syncthreads();
    }
    int excl = (t == 0) ? 0 : scn[t - 1];
    lcur[t] = excl;
    if (t < nn) {
        rowptr[base + t] = lo + excl;
        dinv[base + t] = rsqrtf((float)(mydeg + 1));  // +1 = self-loop
    }
    if (b == nbuck - 1 && t == 0) rowptr[N] = hi;
    __syncthreads();
    if (cnt <= CSR_CAP) {
        for (int i = t; i < cnt; i += 256) {
            uint p = pairbuf[lo + i];
            int pos = atomicAdd(&lcur[p >> 24], 1);
            lcsr[pos] = (int)(p & 0xFFFFFFu);
        }
        __syncthreads();
        for (int i = t; i < cnt; i += 256) csr[lo + i] = lcsr[i];
    } else {
        for (int i = t; i < cnt; i += 256) {
            uint p = pairbuf[lo + i];
            int pos = lo + atomicAdd(&lcur[p >> 24], 1);
            csr[pos] = (int)(p & 0xFFFFFFu);
        }
    }
}

// ---------------- weight transpose+cast (one kernel for W1, Wm, W2) ----------------
// w1t/wmt: [128][128] (n-major); w2t: [48][128] zero-padded (40 real cols).

__global__ void k_castT_all(const float* __restrict__ W1, const float* __restrict__ Wm,
                            const float* __restrict__ W2, ushort* __restrict__ w1t,
                            ushort* __restrict__ wmt, ushort* __restrict__ w2t) {
    int b = blockIdx.x;
    int t = threadIdx.x;
    if (b < 64) {
        int i = b * 256 + t; int k = i >> 7, n = i & 127;
        w1t[n * 128 + k] = bf16rne(W1[k * 128 + n]);
    } else if (b < 128) {
        int i = (b - 64) * 256 + t; int k = i >> 7, n = i & 127;
        wmt[n * 128 + k] = bf16rne(Wm[k * 128 + n]);
    } else {
        int i = (b - 128) * 256 + t;  // 0..6143 over [48][128]
        if (i < 6144) {
            int n = i >> 7, k = i & 127;
            w2t[n * 128 + k] = (n < 40) ? bf16rne(W2[k * 40 + n]) : (ushort)0;
        }
    }
}

// ---------------- layer-1 GEMM: C[M x 128](bf16) = (f32 x @ W1) * dinv[row] ----------------

__global__ __launch_bounds__(256) void k_gemm1(const float* __restrict__ A,
                                               const ushort* __restrict__ Wt,
                                               const float* __restrict__ dinv,
                                               ushort* __restrict__ C, int M) {
    int t = threadIdx.x;
    int wave = t >> 6, lane = t & 63;
    int m16 = lane & 15, quad = lane >> 4;
    int rowA = blockIdx.x * 64 + wave * 16 + m16;
    int rA = min(rowA, M - 1);
    const float4* A4 = (const float4*)A;  // 32 float4 per row

    f32x4 acc[8];
#pragma unroll
    for (int i = 0; i < 8; i++) acc[i] = (f32x4){0.f, 0.f, 0.f, 0.f};

#pragma unroll
    for (int it = 0; it < 4; it++) {
        float4 f0 = A4[(size_t)rA * 32 + 8 * it + 2 * quad];
        float4 f1 = A4[(size_t)rA * 32 + 8 * it + 2 * quad + 1];
        bf16x8 af;
        af[0] = (short)bf16rne(f0.x); af[1] = (short)bf16rne(f0.y);
        af[2] = (short)bf16rne(f0.z); af[3] = (short)bf16rne(f0.w);
        af[4] = (short)bf16rne(f1.x); af[5] = (short)bf16rne(f1.y);
        af[6] = (short)bf16rne(f1.z); af[7] = (short)bf16rne(f1.w);
#pragma unroll
        for (int nt = 0; nt < 8; nt++) {
            bf16x8 bfr = *(const bf16x8*)(Wt + (size_t)(nt * 16 + m16) * 128 + it * 32 + quad * 8);
            acc[nt] = __builtin_amdgcn_mfma_f32_16x16x32_bf16(af, bfr, acc[nt], 0, 0, 0);
        }
    }
    int rowBase = blockIdx.x * 64 + wave * 16 + quad * 4;
    float dnv[4];
#pragma unroll
    for (int r = 0; r < 4; r++) dnv[r] = dinv[min(rowBase + r, M - 1)];
#pragma unroll
    for (int nt = 0; nt < 8; nt++) {
        int col = nt * 16 + m16;
#pragma unroll
        for (int r = 0; r < 4; r++) {
            int row = rowBase + r;
            if (row < M) C[(size_t)row * 128 + col] = bf16rne(acc[nt][r] * dnv[r]);
        }
    }
}

// ---------------- fused agg + GEMM (v4: wave-local, no block barrier) ----------------
// Each wave owns 8 rows: 4 groups x 16 lanes, each group aggregates 2 nodes
// (coalesced: 16 lanes x uint4 = one 256B row per load inst, x4 edge unroll),
// writes its rows to a wave-private LDS strip, threadfence_block (lgkmcnt
// drain, NO __syncthreads), then the wave alone runs MFMA over an A-tile with
// 8 valid rows (m16>=8 lanes supply zero frags; quads 2,3 skip stores).
// Waves never wait on each other -> gather requests stay in flight for the
// whole kernel lifetime (fixes the R10 phase-serialization BW dilution).

template <int NT>  // n-tiles in Wt (8 -> 128 cols, 3 -> 48/40 cols)
__device__ __forceinline__ void fused_agg_gemm(const ushort* __restrict__ gsrc,
                                               const float* __restrict__ dinv,
                                               const int* __restrict__ rowptr,
                                               const int* __restrict__ csr,
                                               const float* __restrict__ bias,
                                               const ushort* __restrict__ Wt,
                                               ushort* __restrict__ C,
                                               int M, int ccols) {
    __shared__ ushort hs[4][8][136];
    int t = threadIdx.x;
    int wave = t >> 6, lane = t & 63;
    int grp = (lane >> 4) & 3;
    int l = lane & 15;
    const uint4* g16 = (const uint4*)gsrc;  // 16 uint4 per 128-bf16 row
    float4 bb0 = ((const float4*)bias)[2 * l];
    float4 bb1 = ((const float4*)bias)[2 * l + 1];
    int waveRow0 = blockIdx.x * 32 + wave * 8;

#pragma unroll
    for (int q = 0; q < 2; q++) {
        int node = waveRow0 + grp * 2 + q;
        int nd = min(node, M - 1);
        float dn = dinv[nd];
        float a[8];
        {
            uint4 p = g16[(size_t)nd * 16 + l];
            unpack2(p.x, a[0], a[1]); unpack2(p.y, a[2], a[3]);
            unpack2(p.z, a[4], a[5]); unpack2(p.w, a[6], a[7]);
        }
        int e0 = rowptr[nd], e1 = rowptr[nd + 1];
        int e = e0;
        for (; e + 4 <= e1; e += 4) {
            int s0 = csr[e], s1 = csr[e + 1], s2 = csr[e + 2], s3 = csr[e + 3];
            uint4 p0 = g16[(size_t)s0 * 16 + l];
            uint4 p1 = g16[(size_t)s1 * 16 + l];
            uint4 p2 = g16[(size_t)s2 * 16 + l];
            uint4 p3 = g16[(size_t)s3 * 16 + l];
            float u, v;
            unpack2(p0.x, u, v); a[0] += u; a[1] += v;
            unpack2(p0.y, u, v); a[2] += u; a[3] += v;
            unpack2(p0.z, u, v); a[4] += u; a[5] += v;
            unpack2(p0.w, u, v); a[6] += u; a[7] += v;
            unpack2(p1.x, u, v); a[0] += u; a[1] += v;
            unpack2(p1.y, u, v); a[2] += u; a[3] += v;
            unpack2(p1.z, u, v); a[4] += u; a[5] += v;
            unpack2(p1.w, u, v); a[6] += u; a[7] += v;
            unpack2(p2.x, u, v); a[0] += u; a[1] += v;
            unpack2(p2.y, u, v); a[2] += u; a[3] += v;
            unpack2(p2.z, u, v); a[4] += u; a[5] += v;
            unpack2(p2.w, u, v); a[6] += u; a[7] += v;
            unpack2(p3.x, u, v); a[0] += u; a[1] += v;
            unpack2(p3.y, u, v); a[2] += u; a[3] += v;
            unpack2(p3.z, u, v); a[4] += u; a[5] += v;
            unpack2(p3.w, u, v); a[6] += u; a[7] += v;
        }
        for (; e < e1; e++) {
            int s = csr[e];
            uint4 p = g16[(size_t)s * 16 + l];
            float u, v;
            unpack2(p.x, u, v); a[0] += u; a[1] += v;
            unpack2(p.y, u, v); a[2] += u; a[3] += v;
            unpack2(p.z, u, v); a[4] += u; a[5] += v;
            unpack2(p.w, u, v); a[6] += u; a[7] += v;
        }
        float o0 = fmaxf(a[0] * dn + bb0.x, 0.f);
        float o1 = fmaxf(a[1] * dn + bb0.y, 0.f);
        float o2 = fmaxf(a[2] * dn + bb0.z, 0.f);
        float o3 = fmaxf(a[3] * dn + bb0.w, 0.f);
        float o4 = fmaxf(a[4] * dn + bb1.x, 0.f);
        float o5 = fmaxf(a[5] * dn + bb1.y, 0.f);
        float o6 = fmaxf(a[6] * dn + bb1.z, 0.f);
        float o7 = fmaxf(a[7] * dn + bb1.w, 0.f);
        uint4 qv;
        qv.x = (uint)bf16rne(o0) | ((uint)bf16rne(o1) << 16);
        qv.y = (uint)bf16rne(o2) | ((uint)bf16rne(o3) << 16);
        qv.z = (uint)bf16rne(o4) | ((uint)bf16rne(o5) << 16);
        qv.w = (uint)bf16rne(o6) | ((uint)bf16rne(o7) << 16);
        *(uint4*)&hs[wave][grp * 2 + q][l * 8] = qv;
    }
    __threadfence_block();  // lgkmcnt drain; wave-local visibility (no s_barrier)

    // Wave-local GEMM: A-tile has 8 valid rows (m16 < 8), rest zero.
    int m16 = lane & 15, quad = lane >> 4;
    f32x4 acc[NT];
#pragma unroll
    for (int i = 0; i < NT; i++) acc[i] = (f32x4){0.f, 0.f, 0.f, 0.f};
#pragma unroll
    for (int it = 0; it < 4; it++) {
        bf16x8 af = {0, 0, 0, 0, 0, 0, 0, 0};
        if (m16 < 8) af = *(const bf16x8*)&hs[wave][m16][it * 32 + quad * 8];
#pragma unroll
        for (int nt = 0; nt < NT; nt++) {
            bf16x8 bfr = *(const bf16x8*)(Wt + (size_t)(nt * 16 + m16) * 128 + it * 32 + quad * 8);
            acc[nt] = __builtin_amdgcn_mfma_f32_16x16x32_bf16(af, bfr, acc[nt], 0, 0, 0);
        }
    }
    if (quad < 2) {  // D rows 0..7 only
        int rowBase = waveRow0 + quad * 4;
        float dnv[4];
#pragma unroll
        for (int r = 0; r < 4; r++) dnv[r] = dinv[min(rowBase + r, M - 1)];
#pragma unroll
        for (int nt = 0; nt < NT; nt++) {
            int col = nt * 16 + m16;
            if (col >= ccols) continue;
#pragma unroll
            for (int r = 0; r < 4; r++) {
                int row = rowBase + r;
                if (row < M) C[(size_t)row * ccols + col] = bf16rne(acc[nt][r] * dnv[r]);
            }
        }
    }
}

__global__ __launch_bounds__(256) void k_fusedA(const ushort* __restrict__ g,
                                                const float* __restrict__ dinv,
                                                const int* __restrict__ rowptr,
                                                const int* __restrict__ csr,
                                                const float* __restrict__ bias,
                                                const ushort* __restrict__ Wt,
                                                ushort* __restrict__ C, int M) {
    fused_agg_gemm<8>(g, dinv, rowptr, csr, bias, Wt, C, M, 128);
}

__global__ __launch_bounds__(256) void k_fusedB(const ushort* __restrict__ g,
                                                const float* __restrict__ dinv,
                                                const int* __restrict__ rowptr,
                                                const int* __restrict__ csr,
                                                const float* __restrict__ bias,
                                                const ushort* __restrict__ Wt,
                                                ushort* __restrict__ C, int M) {
    fused_agg_gemm<3>(g, dinv, rowptr, csr, bias, Wt, C, M, 40);
}

// ---------------- final aggregation over 40-col rows ----------------
// 40-bf16 rows (80 B) = 10 lanes x uint2; 25 nodes per block; x4 unroll; fp32 out.

__global__ __launch_bounds__(256) void k_agg40_b(const ushort* __restrict__ g3,
                                                 const float* __restrict__ dinv,
                                                 const int* __restrict__ rowptr,
                                                 const int* __restrict__ csr,
                                                 const float* __restrict__ bias,
                                                 float* __restrict__ out, int N) {
    int t = threadIdx.x;
    if (t >= 250) return;
    int grp = t / 10;
    int l = t - grp * 10;
    int node = blockIdx.x * 25 + grp;
    if (node >= N) return;
    const uint2* gp = (const uint2*)g3;  // 10 uint2 per 40-bf16 row
    float dn = dinv[node];
    float a0, a1, a2, a3;
    {
        uint2 p = gp[(size_t)node * 10 + l];
        unpack2(p.x, a0, a1);
        unpack2(p.y, a2, a3);
    }
    int e0 = rowptr[node], e1 = rowptr[node + 1];
    int e = e0;
    for (; e + 4 <= e1; e += 4) {
        int s0 = csr[e], s1 = csr[e + 1], s2 = csr[e + 2], s3 = csr[e + 3];
        uint2 p0 = gp[(size_t)s0 * 10 + l];
        uint2 p1 = gp[(size_t)s1 * 10 + l];
        uint2 p2 = gp[(size_t)s2 * 10 + l];
        uint2 p3 = gp[(size_t)s3 * 10 + l];
        float u, v;
        unpack2(p0.x, u, v); a0 += u; a1 += v;
        unpack2(p0.y, u, v); a2 += u; a3 += v;
        unpack2(p1.x, u, v); a0 += u; a1 += v;
        unpack2(p1.y, u, v); a2 += u; a3 += v;
        unpack2(p2.x, u, v); a0 += u; a1 += v;
        unpack2(p2.y, u, v); a2 += u; a3 += v;
        unpack2(p3.x, u, v); a0 += u; a1 += v;
        unpack2(p3.y, u, v); a2 += u; a3 += v;
    }
    for (; e < e1; e++) {
        int s = csr[e];
        uint2 p = gp[(size_t)s * 10 + l];
        float u, v;
        unpack2(p.x, u, v); a0 += u; a1 += v;
        unpack2(p.y, u, v); a2 += u; a3 += v;
    }
    float4 bb = ((const float4*)bias)[l];
    float4 o;
    o.x = a0 * dn + bb.x;
    o.y = a1 * dn + bb.y;
    o.z = a2 * dn + bb.z;
    o.w = a3 * dn + bb.w;
    ((float4*)out)[(size_t)node * 10 + l] = o;
}

// ---------------- launch ----------------

extern "C" void kernel_launch(void* const* d_in, const int* in_sizes, int n_in,
                              void* d_out, int out_size, void* d_ws, size_t ws_size,
                              hipStream_t stream) {
    const float* x  = (const float*)d_in[0];
    const int* eidx = (const int*)d_in[1];
    const float* W1 = (const float*)d_in[2];
    const float* b1 = (const float*)d_in[3];
    const float* Wm = (const float*)d_in[4];
    const float* bm = (const float*)d_in[5];
    const float* W2 = (const float*)d_in[6];
    const float* b2 = (const float*)d_in[7];
    float* out = (float*)d_out;

    int N = in_sizes[0] / 128;
    int E = in_sizes[1] / 2;
    const int* src = eidx;
    const int* dst = eidx + E;
    int nbuck = (N + 255) >> 8;

    char* ws = (char*)d_ws;
    size_t off = 0;
    auto alloc = [&](size_t bytes) -> void* {
        void* p = ws + off;
        off += (bytes + 255) & ~(size_t)255;
        return p;
    };
    float*  dinv    = (float*)alloc((size_t)N * 4);
    int*    rowptr  = (int*)alloc(((size_t)N + 1) * 4);
    int*    csr     = (int*)alloc((size_t)E * 4);
    uint*   pairbuf = (uint*)alloc((size_t)E * 4);
    int*    bcnt    = (int*)alloc(512 * 4);
    int*    bbase   = (int*)alloc(513 * 4);
    int*    bcur    = (int*)alloc(512 * 4);
    ushort* w1t     = (ushort*)alloc(128 * 128 * 2);
    ushort* wmt     = (ushort*)alloc(128 * 128 * 2);
    ushort* w2t     = (ushort*)alloc(48 * 128 * 2);
    ushort* gbuf    = (ushort*)alloc((size_t)N * 128 * 2);
    ushort* gbuf2   = (ushort*)alloc((size_t)N * 128 * 2);
    ushort* g3      = (ushort*)alloc((size_t)N * 40 * 2);

    hipMemsetAsync(bcnt, 0, 512 * 4, stream);
    k_bhist<<<(E + 4095) / 4096, 256, 0, stream>>>(dst, bcnt, E);
    k_bscan<<<1, 512, 0, stream>>>(bcnt, bbase, bcur, nbuck);
    k_binpack<<<(E + 4095) / 4096, 256, 0, stream>>>(src, dst, bcur, pairbuf, E, nbuck);
    k_csrbuild<<<nbuck, 256, 0, stream>>>(pairbuf, bbase, rowptr, dinv, csr, N, nbuck);
    k_castT_all<<<152, 256, 0, stream>>>(W1, Wm, W2, w1t, wmt, w2t);

    int gblk64 = (N + 63) / 64;
    int gblk32 = (N + 31) / 32;
    // layer 1 GEMM (fp32 in, pre-scaled bf16 out)
    k_gemm1<<<gblk64, 256, 0, stream>>>(x, w1t, dinv, gbuf, N);
    // layer-1 agg + layer-2 GEMM fused (wave-local)
    k_fusedA<<<gblk32, 256, 0, stream>>>(gbuf, dinv, rowptr, csr, b1, wmt, gbuf2, N);
    // layer-2 agg + layer-3 GEMM fused (wave-local)
    k_fusedB<<<gblk32, 256, 0, stream>>>(gbuf2, dinv, rowptr, csr, bm, w2t, g3, N);
    // final aggregation
    k_agg40_b<<<(N + 24) / 25, 256, 0, stream>>>(g3, dinv, rowptr, csr, b2, out, N);
}

// Round 12
// 382.532 us; speedup vs baseline: 1.1209x; 1.1209x over previous
//
#include <hip/hip_runtime.h>
#include <hip/hip_bf16.h>

typedef __attribute__((ext_vector_type(8))) short bf16x8;
typedef __attribute__((ext_vector_type(4))) float f32x4;

__device__ __forceinline__ ushort bf16rne(float f) {
    uint u = __float_as_uint(f);
    return (ushort)((u + 0x7fffu + ((u >> 16) & 1u)) >> 16);
}
__device__ __forceinline__ void unpack2(uint p, float& a, float& b) {
    a = __uint_as_float(p << 16);
    b = __uint_as_float(p & 0xffff0000u);
}

// ---------------- bucketed graph preprocessing ----------------
// bucket = dst >> 8 (256 nodes per bucket), nbuck <= 512. Packed pair:
// (dst&255)<<24 | src  (src < 2^24).

__global__ __launch_bounds__(256) void k_bhist(const int* __restrict__ dst,
                                               int* __restrict__ bcnt, int E) {
    __shared__ int hist[512];
    int t = threadIdx.x;
    hist[t] = 0; hist[t + 256] = 0;
    __syncthreads();
    int off = blockIdx.x * 4096;
    int cnt = min(4096, E - off);
    for (int i = t; i < cnt; i += 256) atomicAdd(&hist[dst[off + i] >> 8], 1);
    __syncthreads();
    if (hist[t]) atomicAdd(&bcnt[t], hist[t]);
    if (hist[t + 256]) atomicAdd(&bcnt[t + 256], hist[t + 256]);
}

__global__ void k_bscan(const int* __restrict__ bcnt, int* __restrict__ bbase,
                        int* __restrict__ bcur, int nbuck) {
    __shared__ int s[512];
    int t = threadIdx.x;  // 512
    s[t] = (t < nbuck) ? bcnt[t] : 0;
    __syncthreads();
    for (int d = 1; d < 512; d <<= 1) {
        int u = (t >= d) ? s[t - d] : 0;
        __syncthreads();
        if (t >= d) s[t] += u;
        __syncthreads();
    }
    int excl = (t == 0) ? 0 : s[t - 1];
    bbase[t] = excl;
    if (t < nbuck) bcur[t] = excl;
    if (t == 511) bbase[512] = s[511];
}

__global__ __launch_bounds__(256) void k_binpack(const int* __restrict__ src,
                                                 const int* __restrict__ dst,
                                                 int* __restrict__ bcur,
                                                 uint* __restrict__ pairbuf,
                                                 int E, int nbuck) {
    __shared__ int hist[512];
    __shared__ int scn[512];
    __shared__ int cur[512];
    __shared__ int gbase[512];
    __shared__ uint sorted[4096];
    int t = threadIdx.x;
    int off = blockIdx.x * 4096;
    int cnt = min(4096, E - off);

    hist[t] = 0; hist[t + 256] = 0;
    __syncthreads();
    for (int i = t; i < cnt; i += 256) {
        int b = dst[off + i] >> 8;
        atomicAdd(&hist[b], 1);
    }
    __syncthreads();
    scn[t] = hist[t]; scn[t + 256] = hist[t + 256];
    __syncthreads();
    for (int d = 1; d < 256; d <<= 1) {
        int u0 = (t >= d) ? scn[t - d] : 0;
        int u1 = (t >= d) ? scn[256 + t - d] : 0;
        __syncthreads();
        if (t >= d) { scn[t] += u0; scn[256 + t] += u1; }
        __syncthreads();
    }
    int tot0 = scn[255];
    scn[256 + t] += tot0;
    __syncthreads();
    cur[t] = (t == 0) ? 0 : scn[t - 1];
    cur[t + 256] = scn[t + 255];
    if (t < nbuck && hist[t] > 0) gbase[t] = atomicAdd(&bcur[t], hist[t]);
    int t2 = t + 256;
    if (t2 < nbuck && hist[t2] > 0) gbase[t2] = atomicAdd(&bcur[t2], hist[t2]);
    __syncthreads();
    for (int i = t; i < cnt; i += 256) {
        int d = dst[off + i];
        int s = src[off + i];
        int b = d >> 8;
        int pos = atomicAdd(&cur[b], 1);
        sorted[pos] = ((uint)(d & 255) << 24) | (uint)s;
    }
    __syncthreads();
    int wid = t >> 6, lane = t & 63;
    for (int b = wid; b < nbuck; b += 4) {
        int n = hist[b];
        if (n == 0) continue;
        int ls = (b == 0) ? 0 : scn[b - 1];
        int gb = gbase[b];
        for (int j = lane; j < n; j += 64)
            pairbuf[gb + j] = sorted[ls + j];
    }
}

#define CSR_CAP 5632
__global__ __launch_bounds__(256) void k_csrbuild(const uint* __restrict__ pairbuf,
                                                  const int* __restrict__ bbase,
                                                  int* __restrict__ rowptr,
                                                  float* __restrict__ dinv,
                                                  int* __restrict__ csr,
                                                  int N, int nbuck) {
    __shared__ int lhist[256];
    __shared__ int scn[256];
    __shared__ int lcur[256];
    __shared__ int lcsr[CSR_CAP];
    int b = blockIdx.x;
    int base = b << 8;
    int nn = min(256, N - base);
    int lo = bbase[b], hi = bbase[b + 1];
    int cnt = hi - lo;
    int t = threadIdx.x;
    lhist[t] = 0;
    __syncthreads();
    for (int i = t; i < cnt; i += 256) atomicAdd(&lhist[pairbuf[lo + i] >> 24], 1);
    __syncthreads();
    int mydeg = lhist[t];
    scn[t] = mydeg;
    __syncthreads();
    for (int d = 1; d < 256; d <<= 1) {
        int u = (t >= d) ? scn[t - d] : 0;
        __syncthreads();
        if (t >= d) scn[t] += u;
        __syncthreads();
    }
    int excl = (t == 0) ? 0 : scn[t - 1];
    lcur[t] = excl;
    if (t < nn) {
        rowptr[base + t] = lo + excl;
        dinv[base + t] = rsqrtf((float)(mydeg + 1));  // +1 = self-loop
    }
    if (b == nbuck - 1 && t == 0) rowptr[N] = hi;
    __syncthreads();
    if (cnt <= CSR_CAP) {
        for (int i = t; i < cnt; i += 256) {
            uint p = pairbuf[lo + i];
            int pos = atomicAdd(&lcur[p >> 24], 1);
            lcsr[pos] = (int)(p & 0xFFFFFFu);
        }
        __syncthreads();
        for (int i = t; i < cnt; i += 256) csr[lo + i] = lcsr[i];
    } else {
        for (int i = t; i < cnt; i += 256) {
            uint p = pairbuf[lo + i];
            int pos = lo + atomicAdd(&lcur[p >> 24], 1);
            csr[pos] = (int)(p & 0xFFFFFFu);
        }
    }
}

// ---------------- weight transpose+cast (one kernel for W1, Wm, W2) ----------------
// w1t/wmt: [128][128] (n-major); w2t: [48][128] zero-padded (40 real cols).

__global__ void k_castT_all(const float* __restrict__ W1, const float* __restrict__ Wm,
                            const float* __restrict__ W2, ushort* __restrict__ w1t,
                            ushort* __restrict__ wmt, ushort* __restrict__ w2t) {
    int b = blockIdx.x;
    int t = threadIdx.x;
    if (b < 64) {
        int i = b * 256 + t; int k = i >> 7, n = i & 127;
        w1t[n * 128 + k] = bf16rne(W1[k * 128 + n]);
    } else if (b < 128) {
        int i = (b - 64) * 256 + t; int k = i >> 7, n = i & 127;
        wmt[n * 128 + k] = bf16rne(Wm[k * 128 + n]);
    } else {
        int i = (b - 128) * 256 + t;  // 0..6143 over [48][128]
        if (i < 6144) {
            int n = i >> 7, k = i & 127;
            w2t[n * 128 + k] = (n < 40) ? bf16rne(W2[k * 40 + n]) : (ushort)0;
        }
    }
}

// ---------------- layer-1 GEMM: C[M x 128](bf16) = (f32 x @ W1) * dinv[row] ----------------

__global__ __launch_bounds__(256) void k_gemm1(const float* __restrict__ A,
                                               const ushort* __restrict__ Wt,
                                               const float* __restrict__ dinv,
                                               ushort* __restrict__ C, int M) {
    int t = threadIdx.x;
    int wave = t >> 6, lane = t & 63;
    int m16 = lane & 15, quad = lane >> 4;
    int rowA = blockIdx.x * 64 + wave * 16 + m16;
    int rA = min(rowA, M - 1);
    const float4* A4 = (const float4*)A;  // 32 float4 per row

    f32x4 acc[8];
#pragma unroll
    for (int i = 0; i < 8; i++) acc[i] = (f32x4){0.f, 0.f, 0.f, 0.f};

#pragma unroll
    for (int it = 0; it < 4; it++) {
        float4 f0 = A4[(size_t)rA * 32 + 8 * it + 2 * quad];
        float4 f1 = A4[(size_t)rA * 32 + 8 * it + 2 * quad + 1];
        bf16x8 af;
        af[0] = (short)bf16rne(f0.x); af[1] = (short)bf16rne(f0.y);
        af[2] = (short)bf16rne(f0.z); af[3] = (short)bf16rne(f0.w);
        af[4] = (short)bf16rne(f1.x); af[5] = (short)bf16rne(f1.y);
        af[6] = (short)bf16rne(f1.z); af[7] = (short)bf16rne(f1.w);
#pragma unroll
        for (int nt = 0; nt < 8; nt++) {
            bf16x8 bfr = *(const bf16x8*)(Wt + (size_t)(nt * 16 + m16) * 128 + it * 32 + quad * 8);
            acc[nt] = __builtin_amdgcn_mfma_f32_16x16x32_bf16(af, bfr, acc[nt], 0, 0, 0);
        }
    }
    int rowBase = blockIdx.x * 64 + wave * 16 + quad * 4;
    float dnv[4];
#pragma unroll
    for (int r = 0; r < 4; r++) dnv[r] = dinv[min(rowBase + r, M - 1)];
#pragma unroll
    for (int nt = 0; nt < 8; nt++) {
        int col = nt * 16 + m16;
#pragma unroll
        for (int r = 0; r < 4; r++) {
            int row = rowBase + r;
            if (row < M) C[(size_t)row * 128 + col] = bf16rne(acc[nt][r] * dnv[r]);
        }
    }
}

// ---------------- fused agg + GEMM (v5: R10 structure + dynamic work stealing) ----------------
// Agg: 16 groups x 16 lanes claim node indices 0..31 from an LDS counter
// (leader atomicAdd + __shfl broadcast) -> load balance across groups instead
// of max-of-static-pairs. Coalesced gather: 16 lanes x uint4 = one 256B row
// per load inst, x4 edge unroll. Results land in padded LDS [32][136] at the
// claimed row. GEMM: 4 waves = 2 row-halves x 2 n-tile-halves (same as R10).

template <int NT>  // total n-tiles in Wt (8 -> 128 cols, 3 -> 48/40 cols)
__device__ __forceinline__ void fused_agg_gemm(const ushort* __restrict__ g,
                                               const float* __restrict__ dinv,
                                               const int* __restrict__ rowptr,
                                               const int* __restrict__ csr,
                                               const float* __restrict__ bias,
                                               const ushort* __restrict__ Wt,
                                               ushort* __restrict__ C,
                                               int M, int ccols) {
    __shared__ ushort hs[32][136];
    __shared__ int nextNode;
    int t = threadIdx.x;
    if (t == 0) nextNode = 0;
    int l = t & 15;
    const uint4* g16 = (const uint4*)g;  // 16 uint4 per 128-bf16 row
    float4 bb0 = ((const float4*)bias)[2 * l];
    float4 bb1 = ((const float4*)bias)[2 * l + 1];
    __syncthreads();

    for (;;) {
        int idx = 0;
        if (l == 0) idx = atomicAdd(&nextNode, 1);
        // broadcast from group leader (lane (t&63)&~15 within this wave)
        idx = __shfl(idx, (t & 63) & ~15, 64);
        if (idx >= 32) break;
        int node = blockIdx.x * 32 + idx;
        int nd = min(node, M - 1);
        float dn = dinv[nd];
        float a[8];
        {
            uint4 p = g16[(size_t)nd * 16 + l];
            unpack2(p.x, a[0], a[1]); unpack2(p.y, a[2], a[3]);
            unpack2(p.z, a[4], a[5]); unpack2(p.w, a[6], a[7]);
        }
        int e0 = rowptr[nd], e1 = rowptr[nd + 1];
        int e = e0;
        for (; e + 4 <= e1; e += 4) {
            int s0 = csr[e], s1 = csr[e + 1], s2 = csr[e + 2], s3 = csr[e + 3];
            uint4 p0 = g16[(size_t)s0 * 16 + l];
            uint4 p1 = g16[(size_t)s1 * 16 + l];
            uint4 p2 = g16[(size_t)s2 * 16 + l];
            uint4 p3 = g16[(size_t)s3 * 16 + l];
            float u, v;
            unpack2(p0.x, u, v); a[0] += u; a[1] += v;
            unpack2(p0.y, u, v); a[2] += u; a[3] += v;
            unpack2(p0.z, u, v); a[4] += u; a[5] += v;
            unpack2(p0.w, u, v); a[6] += u; a[7] += v;
            unpack2(p1.x, u, v); a[0] += u; a[1] += v;
            unpack2(p1.y, u, v); a[2] += u; a[3] += v;
            unpack2(p1.z, u, v); a[4] += u; a[5] += v;
            unpack2(p1.w, u, v); a[6] += u; a[7] += v;
            unpack2(p2.x, u, v); a[0] += u; a[1] += v;
            unpack2(p2.y, u, v); a[2] += u; a[3] += v;
            unpack2(p2.z, u, v); a[4] += u; a[5] += v;
            unpack2(p2.w, u, v); a[6] += u; a[7] += v;
            unpack2(p3.x, u, v); a[0] += u; a[1] += v;
            unpack2(p3.y, u, v); a[2] += u; a[3] += v;
            unpack2(p3.z, u, v); a[4] += u; a[5] += v;
            unpack2(p3.w, u, v); a[6] += u; a[7] += v;
        }
        for (; e < e1; e++) {
            int s = csr[e];
            uint4 p = g16[(size_t)s * 16 + l];
            float u, v;
            unpack2(p.x, u, v); a[0] += u; a[1] += v;
            unpack2(p.y, u, v); a[2] += u; a[3] += v;
            unpack2(p.z, u, v); a[4] += u; a[5] += v;
            unpack2(p.w, u, v); a[6] += u; a[7] += v;
        }
        float o0 = fmaxf(a[0] * dn + bb0.x, 0.f);
        float o1 = fmaxf(a[1] * dn + bb0.y, 0.f);
        float o2 = fmaxf(a[2] * dn + bb0.z, 0.f);
        float o3 = fmaxf(a[3] * dn + bb0.w, 0.f);
        float o4 = fmaxf(a[4] * dn + bb1.x, 0.f);
        float o5 = fmaxf(a[5] * dn + bb1.y, 0.f);
        float o6 = fmaxf(a[6] * dn + bb1.z, 0.f);
        float o7 = fmaxf(a[7] * dn + bb1.w, 0.f);
        uint4 qv;
        qv.x = (uint)bf16rne(o0) | ((uint)bf16rne(o1) << 16);
        qv.y = (uint)bf16rne(o2) | ((uint)bf16rne(o3) << 16);
        qv.z = (uint)bf16rne(o4) | ((uint)bf16rne(o5) << 16);
        qv.w = (uint)bf16rne(o6) | ((uint)bf16rne(o7) << 16);
        *(uint4*)&hs[idx][l * 8] = qv;
    }
    __syncthreads();

    // GEMM from LDS: 4 waves = 2 row-halves x 2 n-tile-halves
    int wave = t >> 6, lane = t & 63;
    int m16 = lane & 15, quad = lane >> 4;
    int rowHalf = wave & 1;
    int ntHalf = wave >> 1;
    constexpr int NTH = (NT + 1) / 2;          // tiles in first half
    int ntStart = ntHalf * NTH;
    int ntEnd = ntHalf ? NT : NTH;

    f32x4 acc[NTH];
#pragma unroll
    for (int i = 0; i < NTH; i++) acc[i] = (f32x4){0.f, 0.f, 0.f, 0.f};
#pragma unroll
    for (int it = 0; it < 4; it++) {
        bf16x8 af = *(const bf16x8*)&hs[rowHalf * 16 + m16][it * 32 + quad * 8];
        for (int nt = ntStart; nt < ntEnd; nt++) {
            bf16x8 bfr = *(const bf16x8*)(Wt + (size_t)(nt * 16 + m16) * 128 + it * 32 + quad * 8);
            acc[nt - ntStart] = __builtin_amdgcn_mfma_f32_16x16x32_bf16(af, bfr, acc[nt - ntStart], 0, 0, 0);
        }
    }
    int rowBase = blockIdx.x * 32 + rowHalf * 16 + quad * 4;
    float dnv[4];
#pragma unroll
    for (int r = 0; r < 4; r++) dnv[r] = dinv[min(rowBase + r, M - 1)];
    for (int nt = ntStart; nt < ntEnd; nt++) {
        int col = nt * 16 + m16;
        if (col >= ccols) continue;
#pragma unroll
        for (int r = 0; r < 4; r++) {
            int row = rowBase + r;
            if (row < M) C[(size_t)row * ccols + col] = bf16rne(acc[nt - ntStart][r] * dnv[r]);
        }
    }
}

__global__ __launch_bounds__(256) void k_fusedA(const ushort* __restrict__ g,
                                                const float* __restrict__ dinv,
                                                const int* __restrict__ rowptr,
                                                const int* __restrict__ csr,
                                                const float* __restrict__ bias,
                                                const ushort* __restrict__ Wt,
                                                ushort* __restrict__ C, int M) {
    fused_agg_gemm<8>(g, dinv, rowptr, csr, bias, Wt, C, M, 128);
}

__global__ __launch_bounds__(256) void k_fusedB(const ushort* __restrict__ g,
                                                const float* __restrict__ dinv,
                                                const int* __restrict__ rowptr,
                                                const int* __restrict__ csr,
                                                const float* __restrict__ bias,
                                                const ushort* __restrict__ Wt,
                                                ushort* __restrict__ C, int M) {
    fused_agg_gemm<3>(g, dinv, rowptr, csr, bias, Wt, C, M, 40);
}

// ---------------- final aggregation over 40-col rows ----------------
// 40-bf16 rows (80 B) = 10 lanes x uint2; 25 nodes per block; x4 unroll; fp32 out.

__global__ __launch_bounds__(256) void k_agg40_b(const ushort* __restrict__ g3,
                                                 const float* __restrict__ dinv,
                                                 const int* __restrict__ rowptr,
                                                 const int* __restrict__ csr,
                                                 const float* __restrict__ bias,
                                                 float* __restrict__ out, int N) {
    int t = threadIdx.x;
    if (t >= 250) return;
    int grp = t / 10;
    int l = t - grp * 10;
    int node = blockIdx.x * 25 + grp;
    if (node >= N) return;
    const uint2* gp = (const uint2*)g3;  // 10 uint2 per 40-bf16 row
    float dn = dinv[node];
    float a0, a1, a2, a3;
    {
        uint2 p = gp[(size_t)node * 10 + l];
        unpack2(p.x, a0, a1);
        unpack2(p.y, a2, a3);
    }
    int e0 = rowptr[node], e1 = rowptr[node + 1];
    int e = e0;
    for (; e + 4 <= e1; e += 4) {
        int s0 = csr[e], s1 = csr[e + 1], s2 = csr[e + 2], s3 = csr[e + 3];
        uint2 p0 = gp[(size_t)s0 * 10 + l];
        uint2 p1 = gp[(size_t)s1 * 10 + l];
        uint2 p2 = gp[(size_t)s2 * 10 + l];
        uint2 p3 = gp[(size_t)s3 * 10 + l];
        float u, v;
        unpack2(p0.x, u, v); a0 += u; a1 += v;
        unpack2(p0.y, u, v); a2 += u; a3 += v;
        unpack2(p1.x, u, v); a0 += u; a1 += v;
        unpack2(p1.y, u, v); a2 += u; a3 += v;
        unpack2(p2.x, u, v); a0 += u; a1 += v;
        unpack2(p2.y, u, v); a2 += u; a3 += v;
        unpack2(p3.x, u, v); a0 += u; a1 += v;
        unpack2(p3.y, u, v); a2 += u; a3 += v;
    }
    for (; e < e1; e++) {
        int s = csr[e];
        uint2 p = gp[(size_t)s * 10 + l];
        float u, v;
        unpack2(p.x, u, v); a0 += u; a1 += v;
        unpack2(p.y, u, v); a2 += u; a3 += v;
    }
    float4 bb = ((const float4*)bias)[l];
    float4 o;
    o.x = a0 * dn + bb.x;
    o.y = a1 * dn + bb.y;
    o.z = a2 * dn + bb.z;
    o.w = a3 * dn + bb.w;
    ((float4*)out)[(size_t)node * 10 + l] = o;
}

// ---------------- launch ----------------

extern "C" void kernel_launch(void* const* d_in, const int* in_sizes, int n_in,
                              void* d_out, int out_size, void* d_ws, size_t ws_size,
                              hipStream_t stream) {
    const float* x  = (const float*)d_in[0];
    const int* eidx = (const int*)d_in[1];
    const float* W1 = (const float*)d_in[2];
    const float* b1 = (const float*)d_in[3];
    const float* Wm = (const float*)d_in[4];
    const float* bm = (const float*)d_in[5];
    const float* W2 = (const float*)d_in[6];
    const float* b2 = (const float*)d_in[7];
    float* out = (float*)d_out;

    int N = in_sizes[0] / 128;
    int E = in_sizes[1] / 2;
    const int* src = eidx;
    const int* dst = eidx + E;
    int nbuck = (N + 255) >> 8;

    char* ws = (char*)d_ws;
    size_t off = 0;
    auto alloc = [&](size_t bytes) -> void* {
        void* p = ws + off;
        off += (bytes + 255) & ~(size_t)255;
        return p;
    };
    float*  dinv    = (float*)alloc((size_t)N * 4);
    int*    rowptr  = (int*)alloc(((size_t)N + 1) * 4);
    int*    csr     = (int*)alloc((size_t)E * 4);
    uint*   pairbuf = (uint*)alloc((size_t)E * 4);
    int*    bcnt    = (int*)alloc(512 * 4);
    int*    bbase   = (int*)alloc(513 * 4);
    int*    bcur    = (int*)alloc(512 * 4);
    ushort* w1t     = (ushort*)alloc(128 * 128 * 2);
    ushort* wmt     = (ushort*)alloc(128 * 128 * 2);
    ushort* w2t     = (ushort*)alloc(48 * 128 * 2);
    ushort* gbuf    = (ushort*)alloc((size_t)N * 128 * 2);
    ushort* gbuf2   = (ushort*)alloc((size_t)N * 128 * 2);
    ushort* g3      = (ushort*)alloc((size_t)N * 40 * 2);

    hipMemsetAsync(bcnt, 0, 512 * 4, stream);
    k_bhist<<<(E + 4095) / 4096, 256, 0, stream>>>(dst, bcnt, E);
    k_bscan<<<1, 512, 0, stream>>>(bcnt, bbase, bcur, nbuck);
    k_binpack<<<(E + 4095) / 4096, 256, 0, stream>>>(src, dst, bcur, pairbuf, E, nbuck);
    k_csrbuild<<<nbuck, 256, 0, stream>>>(pairbuf, bbase, rowptr, dinv, csr, N, nbuck);
    k_castT_all<<<152, 256, 0, stream>>>(W1, Wm, W2, w1t, wmt, w2t);

    int gblk64 = (N + 63) / 64;
    int gblk32 = (N + 31) / 32;
    // layer 1 GEMM (fp32 in, pre-scaled bf16 out)
    k_gemm1<<<gblk64, 256, 0, stream>>>(x, w1t, dinv, gbuf, N);
    // layer-1 agg + layer-2 GEMM fused (work-stealing)
    k_fusedA<<<gblk32, 256, 0, stream>>>(gbuf, dinv, rowptr, csr, b1, wmt, gbuf2, N);
    // layer-2 agg + layer-3 GEMM fused (work-stealing)
    k_fusedB<<<gblk32, 256, 0, stream>>>(gbuf2, dinv, rowptr, csr, bm, w2t, g3, N);
    // final aggregation
    k_agg40_b<<<(N + 24) / 25, 256, 0, stream>>>(g3, dinv, rowptr, csr, b2, out, N);
}